// Round 1
// baseline (100.879 us; speedup 1.0000x reference)
//
#include <hip/hip_runtime.h>

// Problem constants (from reference)
#define N_VISITS  16384
#define MAX_CODES 64
#define DIM       64

// One wave (64 lanes) per visit. lane == dim index.
// - Load the visit's 64 ids with one coalesced 256B load (lane j gets id j).
// - Broadcast ids with __shfl; gather emb rows coalesced (64 lanes x 4B).
// - Batch 16 masked gathers per chunk so loads stay in flight (no per-row
//   branch, which would force vmcnt(0) serialization).
__global__ __launch_bounds__(256) void visit_mean_kernel(
    const int* __restrict__ code_ids,
    const float* __restrict__ emb,
    float* __restrict__ out)
{
    const int wave_in_block = threadIdx.x >> 6;
    const int lane = threadIdx.x & 63;
    const int visit = blockIdx.x * 4 + wave_in_block;
    if (visit >= N_VISITS) return;

    // lane j holds id j of this visit (coalesced 256B load)
    const int my_id = code_ids[visit * MAX_CODES + lane];

    const unsigned long long valid = __ballot(my_id >= 0);
    const int count = __popcll(valid);

    float sum = 0.0f;

    #pragma unroll
    for (int j0 = 0; j0 < MAX_CODES; j0 += 16) {
        float v[16];
        float m[16];
        #pragma unroll
        for (int k = 0; k < 16; ++k) {
            const int idj  = __shfl(my_id, j0 + k, 64);   // wave-uniform id
            const int safe = (idj >= 0) ? idj : 0;        // clamp for gather
            m[k] = (idj >= 0) ? 1.0f : 0.0f;
            v[k] = emb[(size_t)safe * DIM + lane];        // coalesced row read
        }
        #pragma unroll
        for (int k = 0; k < 16; ++k) {
            sum = fmaf(m[k], v[k], sum);
        }
    }

    const float scale = (count > 0) ? (1.0f / (float)count) : 0.0f;
    out[visit * DIM + lane] = sum * scale;   // coalesced store
}

extern "C" void kernel_launch(void* const* d_in, const int* in_sizes, int n_in,
                              void* d_out, int out_size, void* d_ws, size_t ws_size,
                              hipStream_t stream) {
    const int*   code_ids = (const int*)d_in[0];    // [N_VISITS, MAX_CODES] int32
    const float* emb      = (const float*)d_in[1];  // [NUM_CODES, DIM] fp32
    float*       out      = (float*)d_out;          // [N_VISITS, DIM] fp32

    const int waves_per_block = 4;                  // 256 threads
    const int grid = N_VISITS / waves_per_block;    // 4096 blocks
    visit_mean_kernel<<<grid, 256, 0, stream>>>(code_ids, emb, out);
}

// Round 2
// 100.471 us; speedup vs baseline: 1.0041x; 1.0041x over previous
//
#include <hip/hip_runtime.h>

// Problem constants (from reference)
#define N_VISITS  16384
#define MAX_CODES 64
#define DIM       64

// One wave per visit. Lane decomposition: r = lane>>4 (row slot 0..3),
// t = lane&15 (float4 quarter of the 64-dim row).
// Each wave-wide float4 gather reads 4 table rows (1 KB) in one instruction;
// 16 such loads cover the visit's 64 rows and are ALL issued before any
// accumulation, so the whole 16 KB of gather data is in flight per wave.
__global__ __launch_bounds__(256) void visit_mean_kernel(
    const int* __restrict__ code_ids,
    const float* __restrict__ emb,
    float* __restrict__ out)
{
    const int wave_in_block = threadIdx.x >> 6;
    const int lane = threadIdx.x & 63;
    const int visit = blockIdx.x * 4 + wave_in_block;

    const int r = lane >> 4;   // which of 4 rows this lane reads
    const int t = lane & 15;   // which float4 of the row

    // lane j holds id j of this visit (one coalesced 256B load per wave)
    const int my_id = code_ids[(size_t)visit * MAX_CODES + lane];
    const unsigned long long valid = __ballot(my_id >= 0);
    const int count = __popcll(valid);

    // Phase 1: broadcast the ids each lane needs: id[4*j + r], j=0..15
    int ids[16];
    #pragma unroll
    for (int j = 0; j < 16; ++j) {
        ids[j] = __shfl(my_id, 4 * j + r, 64);
    }

    // Phase 2: issue all 16 float4 gathers (4 rows / 1 KB per instruction)
    float4 v[16];
    #pragma unroll
    for (int j = 0; j < 16; ++j) {
        const int id   = ids[j];
        const int safe = (id >= 0) ? id : 0;
        v[j] = *((const float4*)(emb + (size_t)safe * DIM) + t);
    }

    // Phase 3: masked accumulate (mask recomputed from ids to save VGPRs)
    float4 acc = make_float4(0.f, 0.f, 0.f, 0.f);
    #pragma unroll
    for (int j = 0; j < 16; ++j) {
        const float m = (ids[j] >= 0) ? 1.0f : 0.0f;
        acc.x = fmaf(m, v[j].x, acc.x);
        acc.y = fmaf(m, v[j].y, acc.y);
        acc.z = fmaf(m, v[j].z, acc.z);
        acc.w = fmaf(m, v[j].w, acc.w);
    }

    // Reduce the 4 row-slots (lanes t, t+16, t+32, t+48) via xor-butterfly
    acc.x += __shfl_xor(acc.x, 16, 64);
    acc.y += __shfl_xor(acc.y, 16, 64);
    acc.z += __shfl_xor(acc.z, 16, 64);
    acc.w += __shfl_xor(acc.w, 16, 64);
    acc.x += __shfl_xor(acc.x, 32, 64);
    acc.y += __shfl_xor(acc.y, 32, 64);
    acc.z += __shfl_xor(acc.z, 32, 64);
    acc.w += __shfl_xor(acc.w, 32, 64);

    if (lane < 16) {
        const float scale = (count > 0) ? (1.0f / (float)count) : 0.0f;
        float4 o;
        o.x = acc.x * scale;
        o.y = acc.y * scale;
        o.z = acc.z * scale;
        o.w = acc.w * scale;
        ((float4*)(out + (size_t)visit * DIM))[t] = o;  // 16 lanes x 16B = 256B
    }
}

extern "C" void kernel_launch(void* const* d_in, const int* in_sizes, int n_in,
                              void* d_out, int out_size, void* d_ws, size_t ws_size,
                              hipStream_t stream) {
    const int*   code_ids = (const int*)d_in[0];    // [N_VISITS, MAX_CODES] int32
    const float* emb      = (const float*)d_in[1];  // [NUM_CODES, DIM] fp32
    float*       out      = (float*)d_out;          // [N_VISITS, DIM] fp32

    const int waves_per_block = 4;                  // 256 threads
    const int grid = N_VISITS / waves_per_block;    // 4096 blocks
    visit_mean_kernel<<<grid, 256, 0, stream>>>(code_ids, emb, out);
}